// Round 6
// baseline (530.105 us; speedup 1.0000x reference)
//
#include <hip/hip_runtime.h>
#include <hip/hip_bf16.h>
#include <cmath>

#define N_NODES 8192
#define F_INPUT 59
#define H 128
#define K 32
#define NECK 512
#define GPER 8
#define NG 1024
#define EPS_BN 1e-5f
#define DPITCH 136   // bf16 row pitch (272 B, 16B-aligned)
#define XPITCH 72    // proj x-plane pitch (144 B, 16B-aligned)
#define NBLK 512     // cooperative grid: 2 blocks/CU co-resident

typedef short bf16x8 __attribute__((ext_vector_type(8)));
typedef float f32x16 __attribute__((ext_vector_type(16)));

// truncation hi/lo split
__device__ __forceinline__ void split_bf(float v, short& hi, short& lo) {
    unsigned u = __float_as_uint(v);
    float hif = __uint_as_float(u & 0xffff0000u);
    hi = (short)(u >> 16);
    lo = (short)(__float_as_uint(v - hif) >> 16);
}

// B-frag flat index for 32x32x16: c = ct*32+ln, k = s*16+hf*8+kk
__device__ __forceinline__ int bfrag_idx(int k, int c, int k16) {
    int ct = c >> 5, ln = c & 31;
    int s = k >> 4, hf = (k >> 3) & 1, kk = k & 7;
    return ((((ct * k16 + s) * 2 + hf) * 32 + ln) * 8 + kk);
}

struct KArgs {
    const float *x, *pos, *normal, *mask_t;
    const int   *src;
    const float *lin_w, *lin_b, *src_w, *dst_w;
    const float *posnn_w, *posnn_b, *posnn_g, *posnn_bb;
    const float *attnn_w, *attnn_b, *attnn_g, *attnn_bb;
    const float *neck_w, *neck_b, *neck_g, *neck_bb;
    const float *mlp1_w, *mlp1_b, *mlp1_g, *mlp1_bb;
    const float *mlp2_w, *mlp2_b;
    float2   *vx;
    float    *xdW;
    unsigned *h2;
    short *w3hi, *w3lo, *awhi, *awlo, *nwhi, *nwlo;
    unsigned *bar;     // grid-barrier counters (zeroed by hipMemsetAsync each launch)
    float *out;
};

// Hand-rolled grid barrier: explicit device-scope release/acquire so phase
// outputs are written back from the producer XCD's L2 and re-fetched by
// consumers (G16: per-XCD L2s are not cross-coherent).
__device__ __forceinline__ void grid_barrier(unsigned* bar, int id) {
    __syncthreads();
    if (threadIdx.x == 0) {
        __threadfence();   // agent-scope release (L2 writeback)
        __hip_atomic_fetch_add(&bar[id], 1u, __ATOMIC_ACQ_REL, __HIP_MEMORY_SCOPE_AGENT);
        while (__hip_atomic_load(&bar[id], __ATOMIC_ACQUIRE, __HIP_MEMORY_SCOPE_AGENT) < NBLK)
            __builtin_amdgcn_s_sleep(2);
        __threadfence();   // agent-scope acquire (invalidate stale lines)
    }
    __syncthreads();
}

__global__ __launch_bounds__(256, 2) void mega_kernel(KArgs A)
{
    const int bid  = blockIdx.x;
    const int tid  = threadIdx.x;
    const int wave = tid >> 6;
    const int lane = tid & 63;
    const int hf   = lane >> 5;
    const int ln   = lane & 31;

    __shared__ union {
        struct {
            __align__(16) short xhi[32][XPITCH];
            __align__(16) short xlo[32][XPITCH];
        } proj;
        struct {
            int   srcs[K];
            float rel[K][8];
            __align__(16) short dhi[K][DPITCH];
            __align__(16) short dlo[K][DPITCH];
        } edge;
        struct {
            union {
                struct {
                    __align__(16) short ahi[32][DPITCH];
                    __align__(16) short alo[32][DPITCH];
                } a;
                float red[4][4][256];
            } u;
            float gfeat[4][NECK];
        } neck;
    } sm;

    // ================= Phase 0: prep (verbatim R4) =================
    if (bid < F_INPUT) {
        const int c = tid;
        if (c < H) {
            float a1 = 0.f, a2 = 0.f;
            for (int k = 0; k < H; k++) {
                float wa = A.attnn_w[k * H + c];
                a1 = fmaf(A.src_w[bid * H + k], wa, a1);
                a2 = fmaf(A.dst_w[bid * H + k], wa, a2);
            }
            short hi, lo; int idx;
            split_bf(A.lin_w[bid * H + c], hi, lo);
            idx = bfrag_idx(bid, c, 4);       A.w3hi[idx] = hi; A.w3lo[idx] = lo;
            split_bf(a1, hi, lo);
            idx = bfrag_idx(bid, 128 + c, 4); A.w3hi[idx] = hi; A.w3lo[idx] = lo;
            split_bf(a2, hi, lo);
            idx = bfrag_idx(bid, 256 + c, 4); A.w3hi[idx] = hi; A.w3lo[idx] = lo;
        }
    } else if (bid == F_INPUT) {
        for (int t = tid; t < 5 * 384; t += 256) {
            int k = F_INPUT + t / 384, c = t % 384;
            int idx = bfrag_idx(k, c, 4);
            A.w3hi[idx] = 0; A.w3lo[idx] = 0;
        }
    } else if (bid < F_INPUT + 1 + 64) {
        int idx = (bid - F_INPUT - 1) * 256 + tid;
        int kk = idx & 7; int t = idx >> 3;
        int l2 = t & 31; t >>= 5;
        int hb = t & 1;  t >>= 1;
        int s  = t & 7;  t >>= 3;
        int c = t * 32 + l2, k = s * 16 + hb * 8 + kk;
        short hi, lo; split_bf(A.attnn_w[k * H + c], hi, lo);
        A.awhi[idx] = hi; A.awlo[idx] = lo;
    } else if (bid < F_INPUT + 1 + 64 + 256) {
        int idx = (bid - F_INPUT - 1 - 64) * 256 + tid;
        int kk = idx & 7; int t = idx >> 3;
        int l2 = t & 31; t >>= 5;
        int hb = t & 1;  t >>= 1;
        int s  = t & 7;  t >>= 3;
        int c = t * 32 + l2, k = s * 16 + hb * 8 + kk;
        short hi, lo; split_bf(A.neck_w[k * NECK + c], hi, lo);
        A.nwhi[idx] = hi; A.nwlo[idx] = lo;
    }
    grid_barrier(A.bar, 0);

    // ================= Phase 1: proj MFMA (verbatim R4), 256 tiles =================
    if (bid < 256) {
        const int n0 = bid * 32;
        for (int idx = tid; idx < 32 * F_INPUT; idx += 256) {
            int n = idx / F_INPUT, k = idx - n * F_INPUT;
            short hi, lo; split_bf(A.x[n0 * F_INPUT + idx], hi, lo);
            sm.proj.xhi[n][k] = hi; sm.proj.xlo[n][k] = lo;
        }
        if (tid < 32 * 5) {
            int n = tid / 5, k = F_INPUT + tid % 5;
            sm.proj.xhi[n][k] = 0; sm.proj.xlo[n][k] = 0;
        }
        __syncthreads();

        f32x16 acc[3];
        #pragma unroll
        for (int t = 0; t < 3; t++)
            #pragma unroll
            for (int r = 0; r < 16; r++) acc[t][r] = 0.f;

        #pragma unroll
        for (int s = 0; s < 4; s++) {
            bf16x8 ah = *(const bf16x8*)&sm.proj.xhi[ln][s * 16 + hf * 8];
            bf16x8 al = *(const bf16x8*)&sm.proj.xlo[ln][s * 16 + hf * 8];
            #pragma unroll
            for (int t = 0; t < 3; t++) {
                const int ct = wave + 4 * t;
                const int boff = (((ct * 4 + s) * 2 + hf) * 32 + ln) * 8;
                bf16x8 bh = *(const bf16x8*)&A.w3hi[boff];
                bf16x8 bl = *(const bf16x8*)&A.w3lo[boff];
                acc[t] = __builtin_amdgcn_mfma_f32_32x32x16_bf16(ah, bl, acc[t], 0, 0, 0);
                acc[t] = __builtin_amdgcn_mfma_f32_32x32x16_bf16(al, bh, acc[t], 0, 0, 0);
                acc[t] = __builtin_amdgcn_mfma_f32_32x32x16_bf16(ah, bh, acc[t], 0, 0, 0);
            }
        }
        const int c = wave * 32 + ln;
        const float lb = A.lin_b[c];
        #pragma unroll
        for (int r = 0; r < 16; r++) {
            int node = n0 + (r & 3) + 8 * (r >> 2) + 4 * hf;
            A.vx[node * H + c] = make_float2(acc[1][r], acc[0][r] + lb);
            A.xdW[node * H + c] = acc[2][r];
        }
    }
    grid_barrier(A.bar, 1);

    // ================= Phase 2: edge (16 nodes/block, verbatim R4 body) =================
    {
        const int c128 = tid & 127;
        float wp[6];
        #pragma unroll
        for (int k = 0; k < 6; k++) wp[k] = A.posnn_w[k * H + c128];
        const float pb  = A.posnn_b[c128];
        const float ps  = A.posnn_g[c128] * rsqrtf(1.f + EPS_BN);
        const float pbb = A.posnn_bb[c128];
        const int cc = wave * 32 + ln;
        const float as_ = A.attnn_g[cc] * rsqrtf(1.f + EPS_BN);
        const float abb = A.attnn_bb[cc];
        const float ab  = A.attnn_b[cc];

        for (int it = 0; it < 16; ++it) {
            const int i = bid * 16 + it;
            if (tid < K) {
                int s = A.src[i * K + tid];
                sm.edge.srcs[tid] = s;
                #pragma unroll
                for (int k = 0; k < 3; k++) {
                    sm.edge.rel[tid][k]     = A.pos[i * 3 + k]    - A.pos[s * 3 + k];
                    sm.edge.rel[tid][k + 3] = A.normal[i * 3 + k] - A.normal[s * 3 + k];
                }
            }
            __syncthreads();

            for (int j = tid >> 7; j < K; j += 2) {
                float acc = pb;
                #pragma unroll
                for (int k = 0; k < 6; k++) acc = fmaf(sm.edge.rel[j][k], wp[k], acc);
                float d = fmaxf(fmaf(acc, ps, pbb), 0.f);
                short hi, lo; split_bf(d, hi, lo);
                sm.edge.dhi[j][c128] = hi; sm.edge.dlo[j][c128] = lo;
            }
            __syncthreads();

            f32x16 acc;
            #pragma unroll
            for (int r = 0; r < 16; r++) acc[r] = 0.f;
            const short* whb = A.awhi + wave * 8 * 2 * 32 * 8;
            const short* wlb = A.awlo + wave * 8 * 2 * 32 * 8;
            #pragma unroll
            for (int s = 0; s < 8; s++) {
                bf16x8 ah = *(const bf16x8*)&sm.edge.dhi[ln][s * 16 + hf * 8];
                bf16x8 al = *(const bf16x8*)&sm.edge.dlo[ln][s * 16 + hf * 8];
                const int boff = ((s * 2 + hf) * 32 + ln) * 8;
                bf16x8 bh = *(const bf16x8*)&whb[boff];
                bf16x8 bl = *(const bf16x8*)&wlb[boff];
                acc = __builtin_amdgcn_mfma_f32_32x32x16_bf16(ah, bl, acc, 0, 0, 0);
                acc = __builtin_amdgcn_mfma_f32_32x32x16_bf16(al, bh, acc, 0, 0, 0);
                acc = __builtin_amdgcn_mfma_f32_32x32x16_bf16(ah, bh, acc, 0, 0, 0);
            }

            const float base = A.xdW[i * H + cc] + ab;
            float a[16], vv[16];
            float m = 0.f;
            #pragma unroll
            for (int r = 0; r < 16; r++) {
                int j = (r & 3) + 8 * (r >> 2) + 4 * hf;
                float2 g = A.vx[sm.edge.srcs[j] * H + cc];
                float al = acc[r] + base - g.x;
                float av = fmaxf(fmaf(al, as_, abb), 0.f);
                a[r] = av; vv[r] = g.y;
                m = fmaxf(m, av);
            }
            m = fmaxf(m, __shfl_xor(m, 32, 64));
            float den = 0.f;
            #pragma unroll
            for (int r = 0; r < 16; r++) {
                float e = __expf(a[r] - m);
                a[r] = e; den += e;
            }
            den += __shfl_xor(den, 32, 64);
            const float inv = 1.f / (den + 1e-16f);

            float hsum = 0.f;
            #pragma unroll
            for (int r = 0; r < 16; r++) {
                int j = (r & 3) + 8 * (r >> 2) + 4 * hf;
                unsigned dh = (unsigned short)sm.edge.dhi[j][cc];
                unsigned dl = (unsigned short)sm.edge.dlo[j][cc];
                float dd = __uint_as_float(dh << 16) + __uint_as_float(dl << 16);
                hsum = fmaf(a[r], vv[r] + dd, hsum);
            }
            hsum += __shfl_xor(hsum, 32, 64);
            hsum *= inv;
            if (hf == 0) {
                unsigned u = __float_as_uint(hsum);
                unsigned hib = u & 0xffff0000u;
                unsigned lo = __float_as_uint(hsum - __uint_as_float(hib)) >> 16;
                A.h2[i * H + cc] = (lo << 16) | (u >> 16);
            }
            __syncthreads();   // guard LDS reuse by next iteration's stage
        }
    }
    grid_barrier(A.bar, 2);

    // ================= Phase 3: neck + pool + head (verbatim R4), 256 tiles =================
    if (bid < 256) {
        const int n0 = bid * 32;
        for (int d = tid; d < 32 * H; d += 256) {
            unsigned u = A.h2[(n0 + (d >> 7)) * H + (d & 127)];
            sm.neck.u.a.ahi[d >> 7][d & 127] = (short)(u & 0xffffu);
            sm.neck.u.a.alo[d >> 7][d & 127] = (short)(u >> 16);
        }
        __syncthreads();

        f32x16 acc[4];
        #pragma unroll
        for (int t = 0; t < 4; t++)
            #pragma unroll
            for (int r = 0; r < 16; r++) acc[t][r] = 0.f;

        #pragma unroll
        for (int s = 0; s < 8; s++) {
            bf16x8 ah = *(const bf16x8*)&sm.neck.u.a.ahi[ln][s * 16 + hf * 8];
            bf16x8 al = *(const bf16x8*)&sm.neck.u.a.alo[ln][s * 16 + hf * 8];
            #pragma unroll
            for (int t = 0; t < 4; t++) {
                const int ct = wave * 4 + t;
                const int boff = (((ct * 8 + s) * 2 + hf) * 32 + ln) * 8;
                bf16x8 bh = *(const bf16x8*)&A.nwhi[boff];
                bf16x8 bl = *(const bf16x8*)&A.nwlo[boff];
                acc[t] = __builtin_amdgcn_mfma_f32_32x32x16_bf16(ah, bl, acc[t], 0, 0, 0);
                acc[t] = __builtin_amdgcn_mfma_f32_32x32x16_bf16(al, bh, acc[t], 0, 0, 0);
                acc[t] = __builtin_amdgcn_mfma_f32_32x32x16_bf16(ah, bh, acc[t], 0, 0, 0);
            }
        }

        #pragma unroll
        for (int t = 0; t < 4; t++) {
            const int c = wave * 128 + t * 32 + ln;
            const float s  = A.neck_g[c] * rsqrtf(1.f + EPS_BN);
            const float bnb = fmaf(A.neck_b[c], s, A.neck_bb[c]);
            #pragma unroll
            for (int g = 0; g < 4; g++) {
                float m = 0.f;
                #pragma unroll
                for (int q = 0; q < 4; q++)
                    m = fmaxf(m, fmaf(acc[t][4 * g + q], s, bnb));
                m = fmaxf(m, __shfl_xor(m, 32, 64));
                if (hf == 0) sm.neck.gfeat[g][c] = m;
            }
        }
        __syncthreads();   // gfeat ready; a-planes dead -> red may alias them

        const int c4 = lane;
        float ph[4][4];
        #pragma unroll
        for (int g = 0; g < 4; g++)
            #pragma unroll
            for (int mm = 0; mm < 4; mm++) ph[g][mm] = 0.f;

        const int k0 = wave * 128;
        for (int k = 0; k < 128; k += 4) {
            float4 gv[4];
            #pragma unroll
            for (int g = 0; g < 4; g++) gv[g] = *(const float4*)&sm.neck.gfeat[g][k0 + k];
            #pragma unroll
            for (int kk = 0; kk < 4; kk++) {
                float w0 = A.mlp1_w[(k0 + k + kk) * 256 + c4];
                float w1 = A.mlp1_w[(k0 + k + kk) * 256 + c4 + 64];
                float w2 = A.mlp1_w[(k0 + k + kk) * 256 + c4 + 128];
                float w3 = A.mlp1_w[(k0 + k + kk) * 256 + c4 + 192];
                #pragma unroll
                for (int g = 0; g < 4; g++) {
                    float gvk = (&gv[g].x)[kk];
                    ph[g][0] = fmaf(gvk, w0, ph[g][0]);
                    ph[g][1] = fmaf(gvk, w1, ph[g][1]);
                    ph[g][2] = fmaf(gvk, w2, ph[g][2]);
                    ph[g][3] = fmaf(gvk, w3, ph[g][3]);
                }
            }
        }
        #pragma unroll
        for (int g = 0; g < 4; g++)
            #pragma unroll
            for (int mm = 0; mm < 4; mm++)
                sm.neck.u.red[wave][g][c4 + 64 * mm] = ph[g][mm];
        __syncthreads();

        {
            const int g = wave;
            float part = 0.f;
            #pragma unroll
            for (int mm = 0; mm < 4; mm++) {
                const int c = c4 + 64 * mm;
                float sum = A.mlp1_b[c] + sm.neck.u.red[0][g][c] + sm.neck.u.red[1][g][c]
                          + sm.neck.u.red[2][g][c] + sm.neck.u.red[3][g][c];
                float s = A.mlp1_g[c] * rsqrtf(1.f + EPS_BN);
                float val = fmaxf(fmaf(sum, s, A.mlp1_bb[c]), 0.f);
                part = fmaf(val, A.mlp2_w[c], part);
            }
            #pragma unroll
            for (int off = 32; off > 0; off >>= 1) part += __shfl_xor(part, off, 64);
            if (lane == 0) {
                const int gg = bid * 4 + g;
                float mm = A.mask_t[gg * GPER];
                #pragma unroll
                for (int n = 1; n < GPER; n++) mm = fmaxf(mm, A.mask_t[gg * GPER + n]);
                A.out[gg] = (mm == 1.0f) ? (part + A.mlp2_b[0]) : 0.f;
            }
        }
    }
}

// ---------------------------------------------------------------------------
extern "C" void kernel_launch(void* const* d_in, const int* in_sizes, int n_in,
                              void* d_out, int out_size, void* d_ws, size_t ws_size,
                              hipStream_t stream)
{
    KArgs A;
    A.x        = (const float*)d_in[0];
    A.pos      = (const float*)d_in[1];
    A.normal   = (const float*)d_in[2];
    A.mask_t   = (const float*)d_in[3];
    A.src      = (const int*)d_in[5];
    A.lin_w    = (const float*)d_in[7];
    A.lin_b    = (const float*)d_in[8];
    A.src_w    = (const float*)d_in[9];
    A.dst_w    = (const float*)d_in[10];
    A.posnn_w  = (const float*)d_in[11];
    A.posnn_b  = (const float*)d_in[12];
    A.posnn_g  = (const float*)d_in[13];
    A.posnn_bb = (const float*)d_in[14];
    A.attnn_w  = (const float*)d_in[15];
    A.attnn_b  = (const float*)d_in[16];
    A.attnn_g  = (const float*)d_in[17];
    A.attnn_bb = (const float*)d_in[18];
    A.neck_w   = (const float*)d_in[19];
    A.neck_b   = (const float*)d_in[20];
    A.neck_g   = (const float*)d_in[21];
    A.neck_bb  = (const float*)d_in[22];
    A.mlp1_w   = (const float*)d_in[23];
    A.mlp1_b   = (const float*)d_in[24];
    A.mlp1_g   = (const float*)d_in[25];
    A.mlp1_bb  = (const float*)d_in[26];
    A.mlp2_w   = (const float*)d_in[27];
    A.mlp2_b   = (const float*)d_in[28];

    float* ws = (float*)d_ws;
    A.vx   = (float2*)ws;
    A.xdW  = (float*)(A.vx + (size_t)N_NODES * H);
    A.h2   = (unsigned*)(A.xdW + (size_t)N_NODES * H);
    A.w3hi = (short*)(A.h2 + (size_t)N_NODES * H);
    A.w3lo = A.w3hi + 24576;
    A.awhi = A.w3lo + 24576;
    A.awlo = A.awhi + H * H;
    A.nwhi = A.awlo + H * H;
    A.nwlo = A.nwhi + H * NECK;
    A.bar  = (unsigned*)(A.nwlo + H * NECK);
    A.out  = (float*)d_out;

    hipMemsetAsync(A.bar, 0, 4 * sizeof(unsigned), stream);

    void* params[] = { (void*)&A };
    hipLaunchCooperativeKernel((const void*)mega_kernel, dim3(NBLK), dim3(256),
                               params, 0, stream);
}

// Round 7
// 202.637 us; speedup vs baseline: 2.6160x; 2.6160x over previous
//
#include <hip/hip_runtime.h>
#include <hip/hip_bf16.h>
#include <cmath>

#define N_NODES 8192
#define F_INPUT 59
#define H 128
#define K 32
#define NECK 512
#define GPER 8
#define NG 1024
#define EPS_BN 1e-5f
#define DPITCH 136   // bf16 row pitch (272 B, 16B-aligned)
#define XPITCH 72    // proj x-plane pitch (144 B, 16B-aligned)

typedef short bf16x8 __attribute__((ext_vector_type(8)));
typedef float f32x16 __attribute__((ext_vector_type(16)));

// truncation hi/lo split
__device__ __forceinline__ void split_bf(float v, short& hi, short& lo) {
    unsigned u = __float_as_uint(v);
    float hif = __uint_as_float(u & 0xffff0000u);
    hi = (short)(u >> 16);
    lo = (short)(__float_as_uint(v - hif) >> 16);
}

// B-frag flat index for 32x32x16: c = ct*32+ln, k = s*16+hf*8+kk
__device__ __forceinline__ int bfrag_idx(int k, int c, int k16) {
    int ct = c >> 5, ln = c & 31;
    int s = k >> 4, hf = (k >> 3) & 1, kk = k & 7;
    return ((((ct * k16 + s) * 2 + hf) * 32 + ln) * 8 + kk);
}

// ---------------------------------------------------------------------------
// Prep (fused):
//   [0,59)   : row f of W3 = [lin_w | src_w@attnn_w | dst_w@attnn_w] -> pack
//   59       : zero-pad W3 rows k=59..63
//   60       : pack posnn_w -> B-frag (K16=1, K padded 6->16)
//   [61,125) : pack attnn_w (K16=8)
//   [125,381): pack neck_w (K16=8)
// ---------------------------------------------------------------------------
__global__ __launch_bounds__(256) void prep_kernel(
    const float* __restrict__ lin_w,
    const float* __restrict__ src_w, const float* __restrict__ dst_w,
    const float* __restrict__ posnn_w,
    const float* __restrict__ attnn_w, const float* __restrict__ neck_w,
    short* __restrict__ w3hi, short* __restrict__ w3lo,
    short* __restrict__ pwhi, short* __restrict__ pwlo,
    short* __restrict__ awhi, short* __restrict__ awlo,
    short* __restrict__ nwhi, short* __restrict__ nwlo)
{
    const int b = blockIdx.x;
    if (b < F_INPUT) {
        const int c = threadIdx.x;
        if (c < H) {
            float a1 = 0.f, a2 = 0.f;
            for (int k = 0; k < H; k++) {
                float wa = attnn_w[k * H + c];
                a1 = fmaf(src_w[b * H + k], wa, a1);
                a2 = fmaf(dst_w[b * H + k], wa, a2);
            }
            short hi, lo; int idx;
            split_bf(lin_w[b * H + c], hi, lo);
            idx = bfrag_idx(b, c, 4);       w3hi[idx] = hi; w3lo[idx] = lo;
            split_bf(a1, hi, lo);
            idx = bfrag_idx(b, 128 + c, 4); w3hi[idx] = hi; w3lo[idx] = lo;
            split_bf(a2, hi, lo);
            idx = bfrag_idx(b, 256 + c, 4); w3hi[idx] = hi; w3lo[idx] = lo;
        }
    } else if (b == F_INPUT) {
        for (int t = threadIdx.x; t < 5 * 384; t += 256) {
            int k = F_INPUT + t / 384, c = t % 384;
            int idx = bfrag_idx(k, c, 4);
            w3hi[idx] = 0; w3lo[idx] = 0;
        }
    } else if (b == F_INPUT + 1) {
        // posnn pack: 2048 entries, K16=1
        for (int idx = threadIdx.x; idx < 2048; idx += 256) {
            int kk = idx & 7; int t = idx >> 3;
            int l2 = t & 31; t >>= 5;
            int hb = t & 1;  t >>= 1;
            int ct = t;                       // 0..3
            int k = hb * 8 + kk, c = ct * 32 + l2;
            float wv = (k < 6) ? posnn_w[k * H + c] : 0.f;
            short hi, lo; split_bf(wv, hi, lo);
            pwhi[idx] = hi; pwlo[idx] = lo;
        }
    } else if (b < F_INPUT + 2 + 64) {
        int idx = (b - F_INPUT - 2) * 256 + threadIdx.x;
        int kk = idx & 7; int t = idx >> 3;
        int l2 = t & 31; t >>= 5;
        int hb = t & 1;  t >>= 1;
        int s  = t & 7;  t >>= 3;
        int c = t * 32 + l2, k = s * 16 + hb * 8 + kk;
        short hi, lo; split_bf(attnn_w[k * H + c], hi, lo);
        awhi[idx] = hi; awlo[idx] = lo;
    } else {
        int idx = (b - F_INPUT - 2 - 64) * 256 + threadIdx.x;
        int kk = idx & 7; int t = idx >> 3;
        int l2 = t & 31; t >>= 5;
        int hb = t & 1;  t >>= 1;
        int s  = t & 7;  t >>= 3;
        int c = t * 32 + l2, k = s * 16 + hb * 8 + kk;
        short hi, lo; split_bf(neck_w[k * NECK + c], hi, lo);
        nwhi[idx] = hi; nwlo[idx] = lo;
    }
}

// ---------------------------------------------------------------------------
// Kernel A: proj via MFMA (verbatim R4). Block = 32 nodes, 4 waves.
// ---------------------------------------------------------------------------
__global__ __launch_bounds__(256) void proj_kernel(
    const float* __restrict__ x, const float* __restrict__ lin_b,
    const short* __restrict__ w3hi, const short* __restrict__ w3lo,
    float2* __restrict__ vx, float* __restrict__ xdW)
{
    const int n0 = blockIdx.x * 32;
    const int tid = threadIdx.x;
    const int wave = tid >> 6;
    const int lane = tid & 63;
    const int hf = lane >> 5;
    const int ln = lane & 31;

    __shared__ __align__(16) short xhi[32][XPITCH];
    __shared__ __align__(16) short xlo[32][XPITCH];

    for (int idx = tid; idx < 32 * F_INPUT; idx += 256) {
        int n = idx / F_INPUT, k = idx - n * F_INPUT;
        short hi, lo; split_bf(x[n0 * F_INPUT + idx], hi, lo);
        xhi[n][k] = hi; xlo[n][k] = lo;
    }
    if (tid < 32 * 5) {
        int n = tid / 5, k = F_INPUT + tid % 5;
        xhi[n][k] = 0; xlo[n][k] = 0;
    }
    __syncthreads();

    f32x16 acc[3];
    #pragma unroll
    for (int t = 0; t < 3; t++)
        #pragma unroll
        for (int r = 0; r < 16; r++) acc[t][r] = 0.f;

    #pragma unroll
    for (int s = 0; s < 4; s++) {
        bf16x8 ah = *(const bf16x8*)&xhi[ln][s * 16 + hf * 8];
        bf16x8 al = *(const bf16x8*)&xlo[ln][s * 16 + hf * 8];
        #pragma unroll
        for (int t = 0; t < 3; t++) {
            const int ct = wave + 4 * t;
            const int boff = (((ct * 4 + s) * 2 + hf) * 32 + ln) * 8;
            bf16x8 bh = *(const bf16x8*)&w3hi[boff];
            bf16x8 bl = *(const bf16x8*)&w3lo[boff];
            acc[t] = __builtin_amdgcn_mfma_f32_32x32x16_bf16(ah, bl, acc[t], 0, 0, 0);
            acc[t] = __builtin_amdgcn_mfma_f32_32x32x16_bf16(al, bh, acc[t], 0, 0, 0);
            acc[t] = __builtin_amdgcn_mfma_f32_32x32x16_bf16(ah, bh, acc[t], 0, 0, 0);
        }
    }
    const int c = wave * 32 + ln;
    const float lb = lin_b[c];
    #pragma unroll
    for (int r = 0; r < 16; r++) {
        int node = n0 + (r & 3) + 8 * (r >> 2) + 4 * hf;
        vx[node * H + c] = make_float2(acc[1][r], acc[0][r] + lb);
        xdW[node * H + c] = acc[2][r];
    }
}

// ---------------------------------------------------------------------------
// Kernel B: edge stage, 2 nodes per block (grid 4096), delta via MFMA.
// Phase a: stage rel (bf16 hi/lo A-frags, K padded to 16) for both nodes.
// Phase b: delta = bn_relu(rel @ posnn_w) via 3-MFMA -> split -> d-planes.
// Phase c: per node, alpha tile via 3-MFMA vs attnn_w, softmax, weighted sum.
// ---------------------------------------------------------------------------
__global__ __launch_bounds__(256) void edge_kernel(
    const float* __restrict__ pos, const float* __restrict__ normal,
    const int* __restrict__ src,
    const float2* __restrict__ vx, const float* __restrict__ xdW,
    const float* __restrict__ posnn_b, const float* __restrict__ posnn_g,
    const float* __restrict__ posnn_bb,
    const float* __restrict__ attnn_b,
    const float* __restrict__ attnn_g, const float* __restrict__ attnn_bb,
    const short* __restrict__ pwhi, const short* __restrict__ pwlo,
    const short* __restrict__ awhi, const short* __restrict__ awlo,
    unsigned* __restrict__ h2)
{
    const int i0 = blockIdx.x * 2;
    const int tid = threadIdx.x;
    const int wave = tid >> 6;
    const int lane = tid & 63;
    const int hf = lane >> 5;
    const int ln = lane & 31;

    __shared__ int srcs[2][K];
    __shared__ __align__(16) short relh[64][16];
    __shared__ __align__(16) short rell[64][16];
    __shared__ __align__(16) short dhi[64][DPITCH];
    __shared__ __align__(16) short dlo[64][DPITCH];

    if (tid < 64) {
        int n = tid >> 5, jj = tid & 31;
        int i = i0 + n;
        int s = src[i * K + jj];
        srcs[n][jj] = s;
        short h_, l_;
        #pragma unroll
        for (int k = 0; k < 3; k++) {
            split_bf(pos[i * 3 + k] - pos[s * 3 + k], h_, l_);
            relh[tid][k] = h_; rell[tid][k] = l_;
            split_bf(normal[i * 3 + k] - normal[s * 3 + k], h_, l_);
            relh[tid][k + 3] = h_; rell[tid][k + 3] = l_;
        }
        #pragma unroll
        for (int k = 6; k < 16; k++) { relh[tid][k] = 0; rell[tid][k] = 0; }
    }

    // per-channel constants (c = cc for this lane)
    const int cc = wave * 32 + ln;
    const float ps  = posnn_g[cc] * rsqrtf(1.f + EPS_BN);
    const float pbn = fmaf(posnn_b[cc], ps, posnn_bb[cc]);
    const float as_ = attnn_g[cc] * rsqrtf(1.f + EPS_BN);
    const float abb = attnn_bb[cc];
    const float ab  = attnn_b[cc];

    // posnn B-frag (K16=1, ct=wave)
    const bf16x8 pbh = *(const bf16x8*)&pwhi[((wave * 2 + hf) * 32 + ln) * 8];
    const bf16x8 pbl = *(const bf16x8*)&pwlo[((wave * 2 + hf) * 32 + ln) * 8];

    __syncthreads();

    // ---- delta via MFMA for both nodes
    #pragma unroll
    for (int n = 0; n < 2; n++) {
        bf16x8 ah = *(const bf16x8*)&relh[32 * n + ln][hf * 8];
        bf16x8 al = *(const bf16x8*)&rell[32 * n + ln][hf * 8];
        f32x16 da;
        #pragma unroll
        for (int r = 0; r < 16; r++) da[r] = 0.f;
        da = __builtin_amdgcn_mfma_f32_32x32x16_bf16(ah, pbl, da, 0, 0, 0);
        da = __builtin_amdgcn_mfma_f32_32x32x16_bf16(al, pbh, da, 0, 0, 0);
        da = __builtin_amdgcn_mfma_f32_32x32x16_bf16(ah, pbh, da, 0, 0, 0);
        #pragma unroll
        for (int r = 0; r < 16; r++) {
            int j = (r & 3) + 8 * (r >> 2) + 4 * hf;
            float d = fmaxf(fmaf(da[r], ps, pbn), 0.f);
            short h_, l_; split_bf(d, h_, l_);
            dhi[32 * n + j][cc] = h_;
            dlo[32 * n + j][cc] = l_;
        }
    }
    __syncthreads();

    // ---- attnn MFMA + softmax epilogue per node
    const short* whb = awhi + wave * 8 * 2 * 32 * 8;
    const short* wlb = awlo + wave * 8 * 2 * 32 * 8;

    #pragma clang loop unroll(disable)
    for (int n = 0; n < 2; n++) {
        const int i = i0 + n;
        f32x16 acc;
        #pragma unroll
        for (int r = 0; r < 16; r++) acc[r] = 0.f;
        #pragma unroll
        for (int s = 0; s < 8; s++) {
            bf16x8 ah = *(const bf16x8*)&dhi[32 * n + ln][s * 16 + hf * 8];
            bf16x8 al = *(const bf16x8*)&dlo[32 * n + ln][s * 16 + hf * 8];
            const int boff = ((s * 2 + hf) * 32 + ln) * 8;
            bf16x8 bh = *(const bf16x8*)&whb[boff];
            bf16x8 bl = *(const bf16x8*)&wlb[boff];
            acc = __builtin_amdgcn_mfma_f32_32x32x16_bf16(ah, bl, acc, 0, 0, 0);
            acc = __builtin_amdgcn_mfma_f32_32x32x16_bf16(al, bh, acc, 0, 0, 0);
            acc = __builtin_amdgcn_mfma_f32_32x32x16_bf16(ah, bh, acc, 0, 0, 0);
        }

        const float base = xdW[i * H + cc] + ab;
        float a[16], vv[16];
        float m = 0.f;   // relu floor
        #pragma unroll
        for (int r = 0; r < 16; r++) {
            int j = (r & 3) + 8 * (r >> 2) + 4 * hf;
            float2 g = vx[srcs[n][j] * H + cc];
            float al2 = acc[r] + base - g.x;
            float av = fmaxf(fmaf(al2, as_, abb), 0.f);
            a[r] = av; vv[r] = g.y;
            m = fmaxf(m, av);
        }
        m = fmaxf(m, __shfl_xor(m, 32, 64));
        float den = 0.f;
        #pragma unroll
        for (int r = 0; r < 16; r++) {
            float e = __expf(a[r] - m);
            a[r] = e; den += e;
        }
        den += __shfl_xor(den, 32, 64);
        const float inv = 1.f / (den + 1e-16f);

        float hsum = 0.f;
        #pragma unroll
        for (int r = 0; r < 16; r++) {
            int j = (r & 3) + 8 * (r >> 2) + 4 * hf;
            unsigned dh = (unsigned short)dhi[32 * n + j][cc];
            unsigned dl = (unsigned short)dlo[32 * n + j][cc];
            float dd = __uint_as_float(dh << 16) + __uint_as_float(dl << 16);
            hsum = fmaf(a[r], vv[r] + dd, hsum);
        }
        hsum += __shfl_xor(hsum, 32, 64);
        hsum *= inv;
        if (hf == 0) {
            unsigned u = __float_as_uint(hsum);
            unsigned hib = u & 0xffff0000u;
            unsigned lo = __float_as_uint(hsum - __uint_as_float(hib)) >> 16;
            h2[i * H + cc] = (lo << 16) | (u >> 16);
        }
    }
}

// ---------------------------------------------------------------------------
// Kernel C (fused): neck MFMA + bn_relu + residue max-pool + head (verbatim R4).
// ---------------------------------------------------------------------------
__global__ __launch_bounds__(256) void neck_head_kernel(
    const unsigned* __restrict__ h2,
    const short* __restrict__ nwhi, const short* __restrict__ nwlo,
    const float* __restrict__ neck_b, const float* __restrict__ neck_g,
    const float* __restrict__ neck_bb,
    const float* __restrict__ mask_t,
    const float* __restrict__ mlp1_w, const float* __restrict__ mlp1_b,
    const float* __restrict__ mlp1_g, const float* __restrict__ mlp1_bb,
    const float* __restrict__ mlp2_w, const float* __restrict__ mlp2_b,
    float* __restrict__ out)
{
    const int blk = blockIdx.x;
    const int n0 = blk * 32;
    const int tid = threadIdx.x;
    const int wave = tid >> 6;
    const int lane = tid & 63;
    const int hf = lane >> 5;
    const int ln = lane & 31;

    __shared__ __align__(16) short a_hi[32][DPITCH];
    __shared__ __align__(16) short a_lo[32][DPITCH];
    __shared__ float gfeat_l[4][NECK];
    __shared__ float red_l[4][4][256];

    for (int d = tid; d < 32 * H; d += 256) {
        unsigned u = h2[(n0 + (d >> 7)) * H + (d & 127)];
        a_hi[d >> 7][d & 127] = (short)(u & 0xffffu);
        a_lo[d >> 7][d & 127] = (short)(u >> 16);
    }
    __syncthreads();

    f32x16 acc[4];
    #pragma unroll
    for (int t = 0; t < 4; t++)
        #pragma unroll
        for (int r = 0; r < 16; r++) acc[t][r] = 0.f;

    #pragma unroll
    for (int s = 0; s < 8; s++) {
        bf16x8 ah = *(const bf16x8*)&a_hi[ln][s * 16 + hf * 8];
        bf16x8 al = *(const bf16x8*)&a_lo[ln][s * 16 + hf * 8];
        #pragma unroll
        for (int t = 0; t < 4; t++) {
            const int ct = wave * 4 + t;
            const int boff = (((ct * 8 + s) * 2 + hf) * 32 + ln) * 8;
            bf16x8 bh = *(const bf16x8*)&nwhi[boff];
            bf16x8 bl = *(const bf16x8*)&nwlo[boff];
            acc[t] = __builtin_amdgcn_mfma_f32_32x32x16_bf16(ah, bl, acc[t], 0, 0, 0);
            acc[t] = __builtin_amdgcn_mfma_f32_32x32x16_bf16(al, bh, acc[t], 0, 0, 0);
            acc[t] = __builtin_amdgcn_mfma_f32_32x32x16_bf16(ah, bh, acc[t], 0, 0, 0);
        }
    }

    #pragma unroll
    for (int t = 0; t < 4; t++) {
        const int c = wave * 128 + t * 32 + ln;
        const float s  = neck_g[c] * rsqrtf(1.f + EPS_BN);
        const float bnb = fmaf(neck_b[c], s, neck_bb[c]);
        #pragma unroll
        for (int g = 0; g < 4; g++) {
            float m = 0.f;
            #pragma unroll
            for (int q = 0; q < 4; q++)
                m = fmaxf(m, fmaf(acc[t][4 * g + q], s, bnb));
            m = fmaxf(m, __shfl_xor(m, 32, 64));
            if (hf == 0) gfeat_l[g][c] = m;
        }
    }
    __syncthreads();

    const int c4 = lane;
    float ph[4][4];
    #pragma unroll
    for (int g = 0; g < 4; g++)
        #pragma unroll
        for (int mm = 0; mm < 4; mm++) ph[g][mm] = 0.f;

    const int k0 = wave * 128;
    for (int k = 0; k < 128; k += 4) {
        float4 gv[4];
        #pragma unroll
        for (int g = 0; g < 4; g++) gv[g] = *(const float4*)&gfeat_l[g][k0 + k];
        #pragma unroll
        for (int kk = 0; kk < 4; kk++) {
            float w0 = mlp1_w[(k0 + k + kk) * 256 + c4];
            float w1 = mlp1_w[(k0 + k + kk) * 256 + c4 + 64];
            float w2 = mlp1_w[(k0 + k + kk) * 256 + c4 + 128];
            float w3 = mlp1_w[(k0 + k + kk) * 256 + c4 + 192];
            #pragma unroll
            for (int g = 0; g < 4; g++) {
                float gvk = (&gv[g].x)[kk];
                ph[g][0] = fmaf(gvk, w0, ph[g][0]);
                ph[g][1] = fmaf(gvk, w1, ph[g][1]);
                ph[g][2] = fmaf(gvk, w2, ph[g][2]);
                ph[g][3] = fmaf(gvk, w3, ph[g][3]);
            }
        }
    }
    #pragma unroll
    for (int g = 0; g < 4; g++)
        #pragma unroll
        for (int mm = 0; mm < 4; mm++)
            red_l[wave][g][c4 + 64 * mm] = ph[g][mm];
    __syncthreads();

    {
        const int g = wave;
        float part = 0.f;
        #pragma unroll
        for (int mm = 0; mm < 4; mm++) {
            const int c = c4 + 64 * mm;
            float sum = mlp1_b[c] + red_l[0][g][c] + red_l[1][g][c]
                      + red_l[2][g][c] + red_l[3][g][c];
            float s = mlp1_g[c] * rsqrtf(1.f + EPS_BN);
            float val = fmaxf(fmaf(sum, s, mlp1_bb[c]), 0.f);
            part = fmaf(val, mlp2_w[c], part);
        }
        #pragma unroll
        for (int off = 32; off > 0; off >>= 1) part += __shfl_xor(part, off, 64);
        if (lane == 0) {
            const int gg = blk * 4 + g;
            float mm = mask_t[gg * GPER];
            #pragma unroll
            for (int n = 1; n < GPER; n++) mm = fmaxf(mm, mask_t[gg * GPER + n]);
            out[gg] = (mm == 1.0f) ? (part + mlp2_b[0]) : 0.f;
        }
    }
}

// ---------------------------------------------------------------------------
extern "C" void kernel_launch(void* const* d_in, const int* in_sizes, int n_in,
                              void* d_out, int out_size, void* d_ws, size_t ws_size,
                              hipStream_t stream)
{
    const float* x        = (const float*)d_in[0];
    const float* pos      = (const float*)d_in[1];
    const float* normal   = (const float*)d_in[2];
    const float* mask_t   = (const float*)d_in[3];
    const int*   src      = (const int*)d_in[5];
    const float* lin_w    = (const float*)d_in[7];
    const float* lin_b    = (const float*)d_in[8];
    const float* src_w    = (const float*)d_in[9];
    const float* dst_w    = (const float*)d_in[10];
    const float* posnn_w  = (const float*)d_in[11];
    const float* posnn_b  = (const float*)d_in[12];
    const float* posnn_g  = (const float*)d_in[13];
    const float* posnn_bb = (const float*)d_in[14];
    const float* attnn_w  = (const float*)d_in[15];
    const float* attnn_b  = (const float*)d_in[16];
    const float* attnn_g  = (const float*)d_in[17];
    const float* attnn_bb = (const float*)d_in[18];
    const float* neck_w   = (const float*)d_in[19];
    const float* neck_b   = (const float*)d_in[20];
    const float* neck_g   = (const float*)d_in[21];
    const float* neck_bb  = (const float*)d_in[22];
    const float* mlp1_w   = (const float*)d_in[23];
    const float* mlp1_b   = (const float*)d_in[24];
    const float* mlp1_g   = (const float*)d_in[25];
    const float* mlp1_bb  = (const float*)d_in[26];
    const float* mlp2_w   = (const float*)d_in[27];
    const float* mlp2_b   = (const float*)d_in[28];

    float* ws = (float*)d_ws;
    float2*   vx   = (float2*)ws;                              // N*H float2
    float*    xdW  = (float*)(vx + (size_t)N_NODES * H);       // N*H
    unsigned* h2   = (unsigned*)(xdW + (size_t)N_NODES * H);   // N*H
    short*    w3hi = (short*)(h2 + (size_t)N_NODES * H);       // 24576
    short*    w3lo = w3hi + 24576;
    short*    pwhi = w3lo + 24576;                             // 2048
    short*    pwlo = pwhi + 2048;
    short*    awhi = pwlo + 2048;                              // 16384
    short*    awlo = awhi + H * H;
    short*    nwhi = awlo + H * H;                             // 65536
    short*    nwlo = nwhi + H * NECK;

    prep_kernel<<<F_INPUT + 2 + 64 + 256, 256, 0, stream>>>(
        lin_w, src_w, dst_w, posnn_w, attnn_w, neck_w,
        w3hi, w3lo, pwhi, pwlo, awhi, awlo, nwhi, nwlo);
    proj_kernel<<<N_NODES / 32, 256, 0, stream>>>(x, lin_b, w3hi, w3lo, vx, xdW);
    edge_kernel<<<N_NODES / 2, 256, 0, stream>>>(pos, normal, src, vx, xdW,
                                                 posnn_b, posnn_g, posnn_bb,
                                                 attnn_b, attnn_g, attnn_bb,
                                                 pwhi, pwlo, awhi, awlo, h2);
    neck_head_kernel<<<N_NODES / 32, 256, 0, stream>>>(
        h2, nwhi, nwlo, neck_b, neck_g, neck_bb, mask_t,
        mlp1_w, mlp1_b, mlp1_g, mlp1_bb, mlp2_w, mlp2_b, (float*)d_out);
}